// Round 16
// baseline (270.385 us; speedup 1.0000x reference)
//
#include <hip/hip_runtime.h>
#include <hip/hip_fp16.h>
#include <math.h>

#define IN_F 512
#define C_DIM 16
#define EF_DIM 64
#define BSHIFT 6     // nodes-per-bucket shift
#define NPB 64       // nodes per bucket; local id fits in 6 bits
#define NBMAX2 2048  // max buckets (N <= 131072: tail fits 17 bits)
#define CNTW 2048    // cnt table row width
#define SCB 512      // scatter/hist partition blocks
#define CAP 2560     // per-bucket sorted-record capacity
// record (8B): { local(6)[22:17] | tail(17)[16:0] , ex f32 }

typedef float f32x4 __attribute__((ext_vector_type(4)));
typedef unsigned u32x2 __attribute__((ext_vector_type(2)));
typedef _Float16 f16x8 __attribute__((ext_vector_type(8)));

union U2H { unsigned u; __half2 h; };

typedef const unsigned __attribute__((address_space(1)))* gas_u32;
typedef unsigned __attribute__((address_space(3)))* las_u32;

__device__ __forceinline__ void gld16(const float* g, float* l) {
  __builtin_amdgcn_global_load_lds((gas_u32)g, (las_u32)l, 16, 0, 0);
}

// ---------------------------------------------------------------------------
// K0: prep. Edge-type logit table he[8]; attention-column weight vectors
// wlt/wrt[512] (f32); 16KB fragment-packed f16 B tables (cols 0-15).
// ---------------------------------------------------------------------------
__global__ __launch_bounds__(512) void prep_kernel(
    const float* __restrict__ W, const float* __restrict__ We,
    const float* __restrict__ al, const float* __restrict__ ar,
    const float* __restrict__ ae, const float* __restrict__ emb,
    const float* __restrict__ resW, float* __restrict__ he,
    _Float16* __restrict__ Bph, _Float16* __restrict__ Bpt,
    float* __restrict__ wlt, float* __restrict__ wrt, int NET) {
  __shared__ float v[EF_DIM];
  int t = threadIdx.x;  // 0..511 == k index
  float wl = 0.f, wr = 0.f;
#pragma unroll
  for (int c = 0; c < C_DIM; c++) {
    float wv = W[t * C_DIM + c];
    wl += wv * al[c];
    wr += wv * ar[c];
  }
  wlt[t] = wl;
  wrt[t] = wr;
  if (t < EF_DIM) {
    float s = 0.f;
    for (int f = 0; f < EF_DIM; f++) s += We[t * EF_DIM + f] * ae[f];
    v[t] = s;
  }
  __syncthreads();
  if (t < NET) {
    float s = 0.f;
    for (int k = 0; k < EF_DIM; k++) s += emb[t * EF_DIM + k] * v[k];
    he[t] = s;
  }
  // B fragments: 8192 f16 per matrix (16KB)
  for (int i = 0; i < 16; i++) {
    int flat = t + 512 * i;
    int j = flat & 7;
    int l = (flat >> 3) & 63;
    int s = flat >> 9;  // 0..15
    int k = 32 * s + ((l >> 4) << 3) + j;
    int c = l & 15;
    Bph[flat] = (_Float16)resW[k * C_DIM + c];
    Bpt[flat] = (_Float16)W[k * C_DIM + c];
  }
}

// ---------------------------------------------------------------------------
// K1: FUSED proj + hist. proj is pinned at the ~3.0TB/s request-path
// ceiling (8 structures, incl. fully-L3-resident replays, all ~135us) with
// all pipes idle -- so the data-independent hist rides along free:
// blocks [0, 2*PB) do proj7 (y = bid>=PB), blocks [2*PB, 2*PB+SCB) do the
// per-(block,bucket) histogram. LDS aliased (32KB both roles).
// ---------------------------------------------------------------------------
__global__ __launch_bounds__(256) void projhist_kernel(
    const float* __restrict__ hf, const float* __restrict__ tf,
    const _Float16* __restrict__ Bph, const _Float16* __restrict__ Bpt,
    const float* __restrict__ wlt, const float* __restrict__ wrt,
    float* __restrict__ resid, float* __restrict__ hl,
    __half* __restrict__ ht_, float* __restrict__ hr, int N, int PB,
    const int* __restrict__ head, unsigned* __restrict__ cnt, int E, int NB,
    int chunk) {
  __shared__ __align__(16) float shmem[8192];  // 32KB: As[2][4096] | lcnt
  int t = threadIdx.x;
  int bid = blockIdx.x;
  if (bid >= 2 * PB) {
    // ---- hist role ----
    unsigned* lcnt = (unsigned*)shmem;
    int hb = bid - 2 * PB;
    for (int b = t; b < NB; b += 256) lcnt[b] = 0u;
    __syncthreads();
    int start = hb * chunk;
    int end = min(E, start + chunk);
    for (int i = start + t; i < end; i += 256)
      atomicAdd(
          &lcnt[((unsigned)__builtin_nontemporal_load(head + i)) >> BSHIFT],
          1u);
    __syncthreads();
    unsigned* row = cnt + (size_t)hb * CNTW;
    for (int b = t; b < NB; b += 256) row[b] = lcnt[b];
    return;
  }
  // ---- proj role (proj7, unchanged) ----
  float* As0 = shmem;
  float* As1 = shmem + 4096;
  int w = __builtin_amdgcn_readfirstlane(t >> 6);
  int lane = t & 63;
  int by = bid >= PB ? 1 : 0;
  int r0 = (bid - by * PB) * 64;
  const float* feat = by ? tf : hf;
  const _Float16* Bp = by ? Bpt : Bph;
  const float* wv = by ? wrt : wlt;
  f32x4 acc0 = {0.f, 0.f, 0.f, 0.f};
  float acc1 = 0.f;
  const float* sg_src[4];
#pragma unroll
  for (int g = 0; g < 4; g++) {
    int u = (w * 4 + g) * 64 + lane;
    int r = u >> 4;
    int c = (u & 15) ^ (r & 7);  // inverse swizzle on global src (rule #21)
    int gr = min(r0 + r, N - 1);
    sg_src[g] = feat + (size_t)gr * IN_F + c * 4;
  }
  int row = w * 16 + (lane & 15);
  int sA[2][2];
#pragma unroll
  for (int s2 = 0; s2 < 2; s2++)
#pragma unroll
    for (int h = 0; h < 2; h++)
      sA[s2][h] = row * 16 + ((s2 * 8 + (lane >> 4) * 2 + h) ^ (row & 7));
  const float* wvp = wv + (lane >> 4) * 8;
#pragma unroll
  for (int g = 0; g < 4; g++) gld16(sg_src[g], As0 + (w * 4 + g) * 256);
  __syncthreads();
#pragma unroll
  for (int kc = 0; kc < 8; kc++) {
    if (kc < 7) {
      float* nb = (kc & 1) ? As0 : As1;
#pragma unroll
      for (int g = 0; g < 4; g++)
        gld16(sg_src[g] + (kc + 1) * 64, nb + (w * 4 + g) * 256);
    }
    const float* ab = (kc & 1) ? As1 : As0;
#pragma unroll
    for (int s2 = 0; s2 < 2; s2++) {
      f32x4 lo = *(const f32x4*)(ab + sA[s2][0] * 4);
      f32x4 hi = *(const f32x4*)(ab + sA[s2][1] * 4);
      f16x8 a = {(_Float16)lo.x, (_Float16)lo.y, (_Float16)lo.z,
                 (_Float16)lo.w, (_Float16)hi.x, (_Float16)hi.y,
                 (_Float16)hi.z, (_Float16)hi.w};
      int s = kc * 2 + s2;
      f16x8 b0 = *(const f16x8*)(Bp + (size_t)(s * 64 + lane) * 8);
      acc0 = __builtin_amdgcn_mfma_f32_16x16x32_f16(a, b0, acc0, 0, 0, 0);
      f32x4 wa = *(const f32x4*)(wvp + kc * 64 + s2 * 32);
      f32x4 wb = *(const f32x4*)(wvp + kc * 64 + s2 * 32 + 4);
      acc1 += lo.x * wa.x + lo.y * wa.y + lo.z * wa.z + lo.w * wa.w +
              hi.x * wb.x + hi.y * wb.y + hi.z * wb.z + hi.w * wb.w;
    }
    __syncthreads();
  }
  acc1 += __shfl_xor(acc1, 16, 64);
  acc1 += __shfl_xor(acc1, 32, 64);
  int col = lane & 15;
  int rb = r0 + w * 16 + (lane >> 4) * 4;
#pragma unroll
  for (int i = 0; i < 4; i++) {
    int r = rb + i;
    if (r < N) {
      if (by == 0)
        resid[(size_t)r * C_DIM + col] = acc0[i];
      else
        ht_[(size_t)r * C_DIM + col] = __float2half(acc0[i]);
    }
  }
  if (lane < 16) {
    int r = r0 + w * 16 + lane;
    if (r < N) {
      if (by == 0)
        hl[r] = acc1;
      else
        hr[r] = acc1;
    }
  }
}

// ---------------------------------------------------------------------------
// K4a: column scan of the (block,bucket) table.
// ---------------------------------------------------------------------------
__global__ __launch_bounds__(256) void colscan_kernel(
    unsigned* __restrict__ cnt, unsigned* __restrict__ btotal, int NB) {
  int b = blockIdx.x * 256 + threadIdx.x;
  if (b >= NB) return;
  unsigned running = 0;
#pragma unroll 8
  for (int blk = 0; blk < SCB; blk++) {
    unsigned v = cnt[(size_t)blk * CNTW + b];
    cnt[(size_t)blk * CNTW + b] = running;
    running += v;
  }
  btotal[b] = running;
}

// ---------------------------------------------------------------------------
// K4b: exclusive scan of bucket totals (<=2048, one block).
// ---------------------------------------------------------------------------
__global__ __launch_bounds__(1024) void scan_kernel(
    const unsigned* __restrict__ btotal, unsigned* __restrict__ base, int NB) {
  __shared__ unsigned ps[1024];
  int t = threadIdx.x;
  unsigned a = (2 * t < NB) ? btotal[2 * t] : 0u;
  unsigned b = (2 * t + 1 < NB) ? btotal[2 * t + 1] : 0u;
  ps[t] = a + b;
  __syncthreads();
  for (int off = 1; off < 1024; off <<= 1) {
    unsigned v = (t >= off) ? ps[t - off] : 0u;
    __syncthreads();
    ps[t] += v;
    __syncthreads();
  }
  unsigned excl = ps[t] - (a + b);
  if (2 * t < NB) base[2 * t] = excl;
  if (2 * t + 1 < NB) base[2 * t + 1] = excl + a;
  if (t == 1023) base[NB] = ps[1023];
}

// ---------------------------------------------------------------------------
// K5: scatter -- full per-edge scalar chain restored (h_l/h_r gathers +
// exp hide under 512-block occupancy here; removing them from agg halves
// agg's per-record dependent-latency chain). 8B record {local|tail, ex}.
// ---------------------------------------------------------------------------
__global__ __launch_bounds__(512) void scatter_kernel(
    const int* __restrict__ head, const int* __restrict__ tail,
    const int* __restrict__ ty, const float* __restrict__ h_l,
    const float* __restrict__ h_r, const float* __restrict__ he_tab,
    const unsigned* __restrict__ cnt, const unsigned* __restrict__ bbase,
    unsigned* __restrict__ rec, int E, int NB, int chunk, int NET) {
  __shared__ unsigned lbase[NBMAX2];
  __shared__ unsigned lcnt[NBMAX2];
  __shared__ float he_s[32];
  int tid = threadIdx.x;
  if (tid < NET) he_s[tid] = he_tab[tid];
  const unsigned* row = cnt + (size_t)blockIdx.x * CNTW;
  for (int b = tid; b < NB; b += 512) {
    lbase[b] = bbase[b] + row[b];
    lcnt[b] = 0u;
  }
  __syncthreads();
  int start = blockIdx.x * chunk;
  int end = min(E, start + chunk);
  for (int i = start + tid; i < end; i += 512) {
    unsigned h = (unsigned)__builtin_nontemporal_load(head + i);
    int tl = __builtin_nontemporal_load(tail + i);
    int t = __builtin_nontemporal_load(ty + i);
    float lg = h_l[h] + h_r[tl] + he_s[t];
    lg = lg > 0.f ? lg : 0.2f * lg;
    float ex = __expf(lg);
    unsigned b = h >> BSHIFT;
    unsigned off = atomicAdd(&lcnt[b], 1u);
    u32x2* dst = (u32x2*)(rec + 2 * (size_t)(lbase[b] + off));
    u32x2 rv;
    rv.x = ((h & 63u) << 17) | (unsigned)tl;
    rv.y = __float_as_uint(ex);
    *dst = rv;
  }
}

// ---------------------------------------------------------------------------
// K6: agg (R14 form) -- 8B records, zero float atomics. LDS counting sort
// by local id, 4-lane-per-node register segmented reduction (+2 shfl_xor),
// fused finalize. Per-record chain is now just rec -> ht gather -> FMA.
// ---------------------------------------------------------------------------
__global__ __launch_bounds__(256) void agg_kernel(
    const unsigned* __restrict__ rec, const unsigned* __restrict__ base,
    const __half* __restrict__ ht, const float* __restrict__ resid,
    const float* __restrict__ resb, float* __restrict__ out, int N) {
  __shared__ __align__(16) unsigned srec[CAP * 2];
  __shared__ unsigned scnt[NPB];
  __shared__ unsigned soff[NPB + 1];
  __shared__ unsigned scur[NPB];
  __shared__ float accf[NPB * 18];
  int tid = threadIdx.x;
  int b = blockIdx.x;
  int s = (int)base[b];
  int e = (int)base[b + 1];
  int cnt_all = e - s;
  int m = min(cnt_all, CAP);
  if (tid < NPB) scnt[tid] = 0u;
  for (int i = tid; i < NPB * 18; i += 256) accf[i] = 0.f;
  __syncthreads();
  for (int i = tid; i < m; i += 256)
    atomicAdd(&scnt[rec[2 * (size_t)(s + i)] >> 17], 1u);
  __syncthreads();
  if (tid < NPB) {
    unsigned v = scnt[tid];
    unsigned orig = v;
    for (int off = 1; off < NPB; off <<= 1) {
      unsigned u = __shfl_up(v, off, 64);
      if (tid >= off) v += u;
    }
    soff[tid + 1] = v;
    scur[tid] = v - orig;
    if (tid == 0) soff[0] = 0u;
  }
  __syncthreads();
  for (int i = tid; i < m; i += 256) {
    u32x2 r = *(const u32x2*)(rec + 2 * (size_t)(s + i));
    unsigned pos = atomicAdd(&scur[r.x >> 17], 1u);
    *(u32x2*)(srec + 2 * pos) = r;
  }
  // overflow fallback (cold; never taken for this input)
  for (int i = CAP + tid; i < cnt_all; i += 256) {
    u32x2 r = *(const u32x2*)(rec + 2 * (size_t)(s + i));
    int local = (int)(r.x >> 17);
    int tl = (int)(r.x & 0x1FFFFu);
    float ex = __uint_as_float(r.y);
    const uint4* hp = (const uint4*)(ht + (size_t)tl * C_DIM);
    uint4 A = hp[0], B = hp[1];
    float* a = accf + local * 18;
    U2H cv;
    float2 f;
    unsigned wvv[8] = {A.x, A.y, A.z, A.w, B.x, B.y, B.z, B.w};
#pragma unroll
    for (int q = 0; q < 8; q++) {
      cv.u = wvv[q];
      f = __half22float2(cv.h);
      atomicAdd(a + 2 * q, ex * f.x);
      atomicAdd(a + 2 * q + 1, ex * f.y);
    }
    atomicAdd(a + 16, ex);
  }
  __syncthreads();
  int w = tid >> 6;
  int lane = tid & 63;
  int node_l = w * 16 + (lane >> 2);
  int p = lane & 3;
  float a[17];
#pragma unroll
  for (int k = 0; k < 17; k++) a[k] = 0.f;
  int st = (int)soff[node_l];
  int en = (int)soff[node_l + 1];
  for (int i = st + p; i < en; i += 4) {
    u32x2 r = *(const u32x2*)(srec + 2 * (size_t)i);
    int tl = (int)(r.x & 0x1FFFFu);
    float ex = __uint_as_float(r.y);
    const uint4* hp = (const uint4*)(ht + (size_t)tl * C_DIM);
    uint4 A = hp[0], B = hp[1];
    U2H cv;
    float2 f;
    unsigned wd[8] = {A.x, A.y, A.z, A.w, B.x, B.y, B.z, B.w};
#pragma unroll
    for (int q = 0; q < 8; q++) {
      cv.u = wd[q];
      f = __half22float2(cv.h);
      a[2 * q] += ex * f.x;
      a[2 * q + 1] += ex * f.y;
    }
    a[16] += ex;
  }
#pragma unroll
  for (int k = 0; k < 17; k++) {
    a[k] += __shfl_xor(a[k], 1, 64);
    a[k] += __shfl_xor(a[k], 2, 64);
  }
  if (p != 0) return;
  int node = (b << BSHIFT) + node_l;
  if (node >= N) return;
  float d = a[16] + accf[node_l * 18 + 16];
  float inv = d > 0.f ? 1.f / d : 0.f;
  const f32x4* r4 = (const f32x4*)(resid + (size_t)node * C_DIM);
  float o[C_DIM];
  float ss = 0.f;
#pragma unroll
  for (int q = 0; q < 4; q++) {
    f32x4 rr = __builtin_nontemporal_load(r4 + q);
    o[4 * q + 0] =
        (a[4 * q + 0] + accf[node_l * 18 + 4 * q + 0]) * inv + rr.x + resb[4 * q + 0];
    o[4 * q + 1] =
        (a[4 * q + 1] + accf[node_l * 18 + 4 * q + 1]) * inv + rr.y + resb[4 * q + 1];
    o[4 * q + 2] =
        (a[4 * q + 2] + accf[node_l * 18 + 4 * q + 2]) * inv + rr.z + resb[4 * q + 2];
    o[4 * q + 3] =
        (a[4 * q + 3] + accf[node_l * 18 + 4 * q + 3]) * inv + rr.w + resb[4 * q + 3];
  }
#pragma unroll
  for (int cc = 0; cc < C_DIM; cc++) ss += o[cc] * o[cc];
  float sc = 1.f / fmaxf(sqrtf(ss), 1e-12f);
  float mx = -1e30f;
#pragma unroll
  for (int cc = 0; cc < C_DIM; cc++) {
    o[cc] *= sc;
    mx = fmaxf(mx, o[cc]);
  }
  float sum = 0.f;
#pragma unroll
  for (int cc = 0; cc < C_DIM; cc++) {
    o[cc] = __expf(o[cc] - mx);
    sum += o[cc];
  }
  float isum = 1.f / sum;
  f32x4* o4 = (f32x4*)(out + (size_t)node * C_DIM);
#pragma unroll
  for (int q = 0; q < 4; q++) {
    f32x4 ov;
    ov.x = o[4 * q] * isum;
    ov.y = o[4 * q + 1] * isum;
    ov.z = o[4 * q + 2] * isum;
    ov.w = o[4 * q + 3] * isum;
    __builtin_nontemporal_store(ov, o4 + q);
  }
}

// ---------------------------------------------------------------------------
extern "C" void kernel_launch(void* const* d_in, const int* in_sizes, int n_in,
                              void* d_out, int out_size, void* d_ws,
                              size_t ws_size, hipStream_t stream) {
  const float* head_feature = (const float*)d_in[0];
  const float* tail_feature = (const float*)d_in[1];
  const int* edge_index = (const int*)d_in[2];
  const int* tmp_edge = (const int*)d_in[3];
  const float* W = (const float*)d_in[4];
  const float* We = (const float*)d_in[5];
  const float* al = (const float*)d_in[6];
  const float* ar = (const float*)d_in[7];
  const float* ae = (const float*)d_in[8];
  const float* emb = (const float*)d_in[9];
  const float* resW = (const float*)d_in[10];
  const float* resb = (const float*)d_in[11];

  const int C = in_sizes[6];           // 16
  const int IN = in_sizes[4] / C;      // 512
  const int N = in_sizes[0] / IN;      // 100000
  const int E = in_sizes[3];           // 3200000
  const int EF = in_sizes[8];          // 64
  const int NET = in_sizes[9] / EF;    // 8
  const int NB = (N + NPB - 1) / NPB;  // 1563
  (void)C; (void)IN; (void)EF; (void)ws_size; (void)out_size; (void)n_in;

  const int* head = edge_index;
  const int* tail = edge_index + E;

  float* ws = (float*)d_ws;
  float* he = ws;                            // 32 f
  _Float16* Bph = (_Float16*)(he + 32);      // 8192 f16 (16KB)
  _Float16* Bpt = Bph + 8192;                // 8192 f16
  float* wlt = (float*)(Bpt + 8192);         // 512 f
  float* wrt = wlt + 512;                    // 512 f
  float* h_l = wrt + 512;                    // N
  float* h_r = h_l + N;                      // N
  __half* ht = (__half*)(h_r + N);           // 16N halves (32B rows, 3.2MB)
  float* resid = (float*)(ht + (size_t)C_DIM * N);  // 16N f32
  unsigned* rec = (unsigned*)(resid + (size_t)C_DIM * N);  // 2E u32 (8B rec)
  unsigned* cnt = rec + 2 * (size_t)E;       // SCB*CNTW
  unsigned* btotal = cnt + (size_t)SCB * CNTW;  // NBMAX2
  unsigned* bbase = btotal + NBMAX2;         // NBMAX2+1

  prep_kernel<<<1, 512, 0, stream>>>(W, We, al, ar, ae, emb, resW, he, Bph,
                                     Bpt, wlt, wrt, NET);
  int PB = (N + 63) / 64;                 // 1563 proj blocks per side
  int chunk = (E + SCB - 1) / SCB;        // hist/scatter partition
  projhist_kernel<<<2 * PB + SCB, 256, 0, stream>>>(
      head_feature, tail_feature, Bph, Bpt, wlt, wrt, resid, h_l, ht, h_r, N,
      PB, head, cnt, E, NB, chunk);
  colscan_kernel<<<(NB + 255) / 256, 256, 0, stream>>>(cnt, btotal, NB);
  scan_kernel<<<1, 1024, 0, stream>>>(btotal, bbase, NB);
  scatter_kernel<<<SCB, 512, 0, stream>>>(head, tail, tmp_edge, h_l, h_r, he,
                                          cnt, bbase, rec, E, NB, chunk, NET);
  agg_kernel<<<NB, 256, 0, stream>>>(rec, bbase, ht, resid, resb,
                                     (float*)d_out, N);
}

// Round 17
// 225.174 us; speedup vs baseline: 1.2008x; 1.2008x over previous
//
#include <hip/hip_runtime.h>
#include <hip/hip_fp16.h>
#include <math.h>

#define IN_F 512
#define C_DIM 16
#define EF_DIM 64
#define BSHIFT 6     // nodes-per-bucket shift
#define NPB 64       // nodes per bucket; local id fits in 6 bits
#define NBMAX2 2048  // max buckets (N <= 131072: tail fits 17 bits)
#define CNTW 2048    // cnt table row width
#define SCB 512      // scatter/hist partition blocks
#define NSPL 8       // colscan splits (SCB/64)
#define CAP 2560     // per-bucket sorted-record capacity
// record (4B): local(6)[25:20] | type(3)[19:17] | tail(17)[16:0]

typedef float f32x4 __attribute__((ext_vector_type(4)));
typedef _Float16 f16x8 __attribute__((ext_vector_type(8)));

union U2H { unsigned u; __half2 h; };

typedef const unsigned __attribute__((address_space(1)))* gas_u32;
typedef unsigned __attribute__((address_space(3)))* las_u32;

__device__ __forceinline__ void gld16(const float* g, float* l) {
  __builtin_amdgcn_global_load_lds((gas_u32)g, (las_u32)l, 16, 0, 0);
}

// ---------------------------------------------------------------------------
// K0: prep. he[8]; attention weight vectors wlt/wrt[512]; 16KB B tables.
// ---------------------------------------------------------------------------
__global__ __launch_bounds__(512) void prep_kernel(
    const float* __restrict__ W, const float* __restrict__ We,
    const float* __restrict__ al, const float* __restrict__ ar,
    const float* __restrict__ ae, const float* __restrict__ emb,
    const float* __restrict__ resW, float* __restrict__ he,
    _Float16* __restrict__ Bph, _Float16* __restrict__ Bpt,
    float* __restrict__ wlt, float* __restrict__ wrt, int NET) {
  __shared__ float v[EF_DIM];
  int t = threadIdx.x;
  float wl = 0.f, wr = 0.f;
#pragma unroll
  for (int c = 0; c < C_DIM; c++) {
    float wv = W[t * C_DIM + c];
    wl += wv * al[c];
    wr += wv * ar[c];
  }
  wlt[t] = wl;
  wrt[t] = wr;
  if (t < EF_DIM) {
    float s = 0.f;
    for (int f = 0; f < EF_DIM; f++) s += We[t * EF_DIM + f] * ae[f];
    v[t] = s;
  }
  __syncthreads();
  if (t < NET) {
    float s = 0.f;
    for (int k = 0; k < EF_DIM; k++) s += emb[t * EF_DIM + k] * v[k];
    he[t] = s;
  }
  for (int i = 0; i < 16; i++) {
    int flat = t + 512 * i;
    int j = flat & 7;
    int l = (flat >> 3) & 63;
    int s = flat >> 9;
    int k = 32 * s + ((l >> 4) << 3) + j;
    int c = l & 15;
    Bph[flat] = (_Float16)resW[k * C_DIM + c];
    Bpt[flat] = (_Float16)W[k * C_DIM + c];
  }
}

// ---------------------------------------------------------------------------
// K1: FUSED proj + hist (R16 form; fusion saved ~4us). proj pinned at the
// ~3TB/s L3/request-path ceiling (8 structures incl. L3-resident replays).
// ---------------------------------------------------------------------------
__global__ __launch_bounds__(256) void projhist_kernel(
    const float* __restrict__ hf, const float* __restrict__ tf,
    const _Float16* __restrict__ Bph, const _Float16* __restrict__ Bpt,
    const float* __restrict__ wlt, const float* __restrict__ wrt,
    float* __restrict__ resid, float* __restrict__ hl,
    __half* __restrict__ ht_, float* __restrict__ hr, int N, int PB,
    const int* __restrict__ head, unsigned* __restrict__ cnt, int E, int NB,
    int chunk) {
  __shared__ __align__(16) float shmem[8192];  // 32KB: As[2][4096] | lcnt
  int t = threadIdx.x;
  int bid = blockIdx.x;
  if (bid >= 2 * PB) {
    unsigned* lcnt = (unsigned*)shmem;
    int hb = bid - 2 * PB;
    for (int b = t; b < NB; b += 256) lcnt[b] = 0u;
    __syncthreads();
    int start = hb * chunk;
    int end = min(E, start + chunk);
    for (int i = start + t; i < end; i += 256)
      atomicAdd(
          &lcnt[((unsigned)__builtin_nontemporal_load(head + i)) >> BSHIFT],
          1u);
    __syncthreads();
    unsigned* row = cnt + (size_t)hb * CNTW;
    for (int b = t; b < NB; b += 256) row[b] = lcnt[b];
    return;
  }
  float* As0 = shmem;
  float* As1 = shmem + 4096;
  int w = __builtin_amdgcn_readfirstlane(t >> 6);
  int lane = t & 63;
  int by = bid >= PB ? 1 : 0;
  int r0 = (bid - by * PB) * 64;
  const float* feat = by ? tf : hf;
  const _Float16* Bp = by ? Bpt : Bph;
  const float* wv = by ? wrt : wlt;
  f32x4 acc0 = {0.f, 0.f, 0.f, 0.f};
  float acc1 = 0.f;
  const float* sg_src[4];
#pragma unroll
  for (int g = 0; g < 4; g++) {
    int u = (w * 4 + g) * 64 + lane;
    int r = u >> 4;
    int c = (u & 15) ^ (r & 7);
    int gr = min(r0 + r, N - 1);
    sg_src[g] = feat + (size_t)gr * IN_F + c * 4;
  }
  int row = w * 16 + (lane & 15);
  int sA[2][2];
#pragma unroll
  for (int s2 = 0; s2 < 2; s2++)
#pragma unroll
    for (int h = 0; h < 2; h++)
      sA[s2][h] = row * 16 + ((s2 * 8 + (lane >> 4) * 2 + h) ^ (row & 7));
  const float* wvp = wv + (lane >> 4) * 8;
#pragma unroll
  for (int g = 0; g < 4; g++) gld16(sg_src[g], As0 + (w * 4 + g) * 256);
  __syncthreads();
#pragma unroll
  for (int kc = 0; kc < 8; kc++) {
    if (kc < 7) {
      float* nb = (kc & 1) ? As0 : As1;
#pragma unroll
      for (int g = 0; g < 4; g++)
        gld16(sg_src[g] + (kc + 1) * 64, nb + (w * 4 + g) * 256);
    }
    const float* ab = (kc & 1) ? As1 : As0;
#pragma unroll
    for (int s2 = 0; s2 < 2; s2++) {
      f32x4 lo = *(const f32x4*)(ab + sA[s2][0] * 4);
      f32x4 hi = *(const f32x4*)(ab + sA[s2][1] * 4);
      f16x8 a = {(_Float16)lo.x, (_Float16)lo.y, (_Float16)lo.z,
                 (_Float16)lo.w, (_Float16)hi.x, (_Float16)hi.y,
                 (_Float16)hi.z, (_Float16)hi.w};
      int s = kc * 2 + s2;
      f16x8 b0 = *(const f16x8*)(Bp + (size_t)(s * 64 + lane) * 8);
      acc0 = __builtin_amdgcn_mfma_f32_16x16x32_f16(a, b0, acc0, 0, 0, 0);
      f32x4 wa = *(const f32x4*)(wvp + kc * 64 + s2 * 32);
      f32x4 wb = *(const f32x4*)(wvp + kc * 64 + s2 * 32 + 4);
      acc1 += lo.x * wa.x + lo.y * wa.y + lo.z * wa.z + lo.w * wa.w +
              hi.x * wb.x + hi.y * wb.y + hi.z * wb.z + hi.w * wb.w;
    }
    __syncthreads();
  }
  acc1 += __shfl_xor(acc1, 16, 64);
  acc1 += __shfl_xor(acc1, 32, 64);
  int col = lane & 15;
  int rb = r0 + w * 16 + (lane >> 4) * 4;
#pragma unroll
  for (int i = 0; i < 4; i++) {
    int r = rb + i;
    if (r < N) {
      if (by == 0)
        resid[(size_t)r * C_DIM + col] = acc0[i];
      else
        ht_[(size_t)r * C_DIM + col] = __float2half(acc0[i]);
    }
  }
  if (lane < 16) {
    int r = r0 + w * 16 + lane;
    if (r < N) {
      if (by == 0)
        hl[r] = acc1;
      else
        hr[r] = acc1;
    }
  }
}

// ---------------------------------------------------------------------------
// K4a: hierarchical column scan, stage A. Old colscan was 1563 threads (7
// blocks) x 512-deep serial -- near-idle GPU. Split blk range into NSPL=8
// segments of 64: 8x parallelism, 64-deep chains.
// ---------------------------------------------------------------------------
__global__ __launch_bounds__(256) void colscanA_kernel(
    unsigned* __restrict__ cnt, unsigned* __restrict__ part, int NB) {
  int b = blockIdx.x * 256 + threadIdx.x;
  if (b >= NB) return;
  int s = blockIdx.y;
  unsigned running = 0;
#pragma unroll 8
  for (int blk = s * 64; blk < s * 64 + 64; blk++) {
    unsigned v = cnt[(size_t)blk * CNTW + b];
    cnt[(size_t)blk * CNTW + b] = running;
    running += v;
  }
  part[(size_t)s * CNTW + b] = running;
}

// K4b: stage B -- exclusive scan of the 8 segment totals per bucket.
__global__ __launch_bounds__(256) void colscanB_kernel(
    unsigned* __restrict__ part, unsigned* __restrict__ btotal, int NB) {
  int b = blockIdx.x * 256 + threadIdx.x;
  if (b >= NB) return;
  unsigned running = 0;
#pragma unroll
  for (int s = 0; s < NSPL; s++) {
    unsigned v = part[(size_t)s * CNTW + b];
    part[(size_t)s * CNTW + b] = running;
    running += v;
  }
  btotal[b] = running;
}

// ---------------------------------------------------------------------------
// K4c: exclusive scan of bucket totals (<=2048, one block).
// ---------------------------------------------------------------------------
__global__ __launch_bounds__(1024) void scan_kernel(
    const unsigned* __restrict__ btotal, unsigned* __restrict__ base, int NB) {
  __shared__ unsigned ps[1024];
  int t = threadIdx.x;
  unsigned a = (2 * t < NB) ? btotal[2 * t] : 0u;
  unsigned b = (2 * t + 1 < NB) ? btotal[2 * t + 1] : 0u;
  ps[t] = a + b;
  __syncthreads();
  for (int off = 1; off < 1024; off <<= 1) {
    unsigned v = (t >= off) ? ps[t - off] : 0u;
    __syncthreads();
    ps[t] += v;
    __syncthreads();
  }
  unsigned excl = ps[t] - (a + b);
  if (2 * t < NB) base[2 * t] = excl;
  if (2 * t + 1 < NB) base[2 * t + 1] = excl + a;
  if (t == 1023) base[NB] = ps[1023];
}

// ---------------------------------------------------------------------------
// K5: scatter -- pure permutation (R15 form; R16's gather-in-scatter was a
// 26us regression). 4B record. Base = bbase + part[split] + cnt[blk].
// ---------------------------------------------------------------------------
__global__ __launch_bounds__(512) void scatter_kernel(
    const int* __restrict__ head, const int* __restrict__ tail,
    const int* __restrict__ ty, const unsigned* __restrict__ cnt,
    const unsigned* __restrict__ part, const unsigned* __restrict__ bbase,
    unsigned* __restrict__ rec, int E, int NB, int chunk) {
  __shared__ unsigned lbase[NBMAX2];
  __shared__ unsigned lcnt[NBMAX2];
  int tid = threadIdx.x;
  int blk = blockIdx.x;
  const unsigned* row = cnt + (size_t)blk * CNTW;
  const unsigned* prow = part + (size_t)(blk >> 6) * CNTW;
  for (int b = tid; b < NB; b += 512) {
    lbase[b] = bbase[b] + prow[b] + row[b];
    lcnt[b] = 0u;
  }
  __syncthreads();
  int start = blk * chunk;
  int end = min(E, start + chunk);
  for (int i = start + tid; i < end; i += 512) {
    unsigned h = (unsigned)__builtin_nontemporal_load(head + i);
    unsigned tl = (unsigned)__builtin_nontemporal_load(tail + i);
    unsigned t = (unsigned)__builtin_nontemporal_load(ty + i);
    unsigned b = h >> BSHIFT;
    unsigned off = atomicAdd(&lcnt[b], 1u);
    rec[lbase[b] + off] = ((h & 63u) << 20) | ((t & 7u) << 17) | tl;
  }
}

// ---------------------------------------------------------------------------
// K6: agg v4 -- 512 threads (8 lanes/node: halves each lane's serial
// gather->exp->FMA chain vs 4 lanes), records read ONCE into statically-
// indexed registers (rule #20) for both histogram and placement. Logit
// recomputed here (h_l LDS window, h_r L2 gather, he LDS). Zero float
// atomics; overflow fallback for buckets > CAP (never taken).
// ---------------------------------------------------------------------------
__global__ __launch_bounds__(512) void agg_kernel(
    const unsigned* __restrict__ rec, const unsigned* __restrict__ base,
    const __half* __restrict__ ht, const float* __restrict__ h_l,
    const float* __restrict__ h_r, const float* __restrict__ he_tab,
    const float* __restrict__ resid, const float* __restrict__ resb,
    float* __restrict__ out, int N, int NET) {
  __shared__ unsigned srec[CAP];
  __shared__ unsigned scnt[NPB];
  __shared__ unsigned soff[NPB + 1];
  __shared__ unsigned scur[NPB];
  __shared__ float accf[NPB * 18];
  __shared__ float hl_s[NPB];
  __shared__ float he_s[8];
  int tid = threadIdx.x;
  int b = blockIdx.x;
  int nodebase = b << BSHIFT;
  int s = (int)base[b];
  int e = (int)base[b + 1];
  int cnt_all = e - s;
  int m = min(cnt_all, CAP);
  if (tid < NPB) {
    scnt[tid] = 0u;
    int node = nodebase + tid;
    hl_s[tid] = node < N ? h_l[node] : 0.f;
  }
  if (tid < NET) he_s[tid] = he_tab[tid];
  for (int i = tid; i < NPB * 18; i += 512) accf[i] = 0.f;
  __syncthreads();
  // records -> registers once (static indices; CAP/512 = 5)
  unsigned rv0 = 0, rv1 = 0, rv2 = 0, rv3 = 0, rv4 = 0;
  if (tid < m) rv0 = rec[(size_t)s + tid];
  if (tid + 512 < m) rv1 = rec[(size_t)s + tid + 512];
  if (tid + 1024 < m) rv2 = rec[(size_t)s + tid + 1024];
  if (tid + 1536 < m) rv3 = rec[(size_t)s + tid + 1536];
  if (tid + 2048 < m) rv4 = rec[(size_t)s + tid + 2048];
  if (tid < m) atomicAdd(&scnt[rv0 >> 20], 1u);
  if (tid + 512 < m) atomicAdd(&scnt[rv1 >> 20], 1u);
  if (tid + 1024 < m) atomicAdd(&scnt[rv2 >> 20], 1u);
  if (tid + 1536 < m) atomicAdd(&scnt[rv3 >> 20], 1u);
  if (tid + 2048 < m) atomicAdd(&scnt[rv4 >> 20], 1u);
  __syncthreads();
  if (tid < NPB) {
    unsigned v = scnt[tid];
    unsigned orig = v;
    for (int off = 1; off < NPB; off <<= 1) {
      unsigned u = __shfl_up(v, off, 64);
      if (tid >= off) v += u;
    }
    soff[tid + 1] = v;
    scur[tid] = v - orig;
    if (tid == 0) soff[0] = 0u;
  }
  __syncthreads();
  if (tid < m) srec[atomicAdd(&scur[rv0 >> 20], 1u)] = rv0;
  if (tid + 512 < m) srec[atomicAdd(&scur[rv1 >> 20], 1u)] = rv1;
  if (tid + 1024 < m) srec[atomicAdd(&scur[rv2 >> 20], 1u)] = rv2;
  if (tid + 1536 < m) srec[atomicAdd(&scur[rv3 >> 20], 1u)] = rv3;
  if (tid + 2048 < m) srec[atomicAdd(&scur[rv4 >> 20], 1u)] = rv4;
  // overflow fallback (cold; never taken for this input)
  for (int i = CAP + tid; i < cnt_all; i += 512) {
    unsigned r = rec[(size_t)(s + i)];
    int local = (int)(r >> 20);
    int typ = (int)((r >> 17) & 7u);
    int tl = (int)(r & 0x1FFFFu);
    float lg = hl_s[local] + h_r[tl] + he_s[typ];
    lg = lg > 0.f ? lg : 0.2f * lg;
    float ex = __expf(lg);
    const uint4* hp = (const uint4*)(ht + (size_t)tl * C_DIM);
    uint4 A = hp[0], B = hp[1];
    float* a = accf + local * 18;
    U2H cv;
    float2 f;
    unsigned wvv[8] = {A.x, A.y, A.z, A.w, B.x, B.y, B.z, B.w};
#pragma unroll
    for (int q = 0; q < 8; q++) {
      cv.u = wvv[q];
      f = __half22float2(cv.h);
      atomicAdd(a + 2 * q, ex * f.x);
      atomicAdd(a + 2 * q + 1, ex * f.y);
    }
    atomicAdd(a + 16, ex);
  }
  __syncthreads();
  int w = tid >> 6;
  int lane = tid & 63;
  int node_l = w * 8 + (lane >> 3);  // 8 lanes per node
  int p = lane & 7;
  float a[17];
#pragma unroll
  for (int k = 0; k < 17; k++) a[k] = 0.f;
  int st = (int)soff[node_l];
  int en = (int)soff[node_l + 1];
  float hlv = hl_s[node_l];
  for (int i = st + p; i < en; i += 8) {
    unsigned r = srec[i];
    int typ = (int)((r >> 17) & 7u);
    int tl = (int)(r & 0x1FFFFu);
    float lg = hlv + h_r[tl] + he_s[typ];
    lg = lg > 0.f ? lg : 0.2f * lg;
    float ex = __expf(lg);
    const uint4* hp = (const uint4*)(ht + (size_t)tl * C_DIM);
    uint4 A = hp[0], B = hp[1];
    U2H cv;
    float2 f;
    unsigned wd[8] = {A.x, A.y, A.z, A.w, B.x, B.y, B.z, B.w};
#pragma unroll
    for (int q = 0; q < 8; q++) {
      cv.u = wd[q];
      f = __half22float2(cv.h);
      a[2 * q] += ex * f.x;
      a[2 * q + 1] += ex * f.y;
    }
    a[16] += ex;
  }
#pragma unroll
  for (int k = 0; k < 17; k++) {
    a[k] += __shfl_xor(a[k], 1, 64);
    a[k] += __shfl_xor(a[k], 2, 64);
    a[k] += __shfl_xor(a[k], 4, 64);
  }
  if (p != 0) return;
  int node = nodebase + node_l;
  if (node >= N) return;
  float d = a[16] + accf[node_l * 18 + 16];
  float inv = d > 0.f ? 1.f / d : 0.f;
  const f32x4* r4 = (const f32x4*)(resid + (size_t)node * C_DIM);
  float o[C_DIM];
  float ss = 0.f;
#pragma unroll
  for (int q = 0; q < 4; q++) {
    f32x4 rr = __builtin_nontemporal_load(r4 + q);
    o[4 * q + 0] =
        (a[4 * q + 0] + accf[node_l * 18 + 4 * q + 0]) * inv + rr.x + resb[4 * q + 0];
    o[4 * q + 1] =
        (a[4 * q + 1] + accf[node_l * 18 + 4 * q + 1]) * inv + rr.y + resb[4 * q + 1];
    o[4 * q + 2] =
        (a[4 * q + 2] + accf[node_l * 18 + 4 * q + 2]) * inv + rr.z + resb[4 * q + 2];
    o[4 * q + 3] =
        (a[4 * q + 3] + accf[node_l * 18 + 4 * q + 3]) * inv + rr.w + resb[4 * q + 3];
  }
#pragma unroll
  for (int cc = 0; cc < C_DIM; cc++) ss += o[cc] * o[cc];
  float sc = 1.f / fmaxf(sqrtf(ss), 1e-12f);
  float mx = -1e30f;
#pragma unroll
  for (int cc = 0; cc < C_DIM; cc++) {
    o[cc] *= sc;
    mx = fmaxf(mx, o[cc]);
  }
  float sum = 0.f;
#pragma unroll
  for (int cc = 0; cc < C_DIM; cc++) {
    o[cc] = __expf(o[cc] - mx);
    sum += o[cc];
  }
  float isum = 1.f / sum;
  f32x4* o4 = (f32x4*)(out + (size_t)node * C_DIM);
#pragma unroll
  for (int q = 0; q < 4; q++) {
    f32x4 ov;
    ov.x = o[4 * q] * isum;
    ov.y = o[4 * q + 1] * isum;
    ov.z = o[4 * q + 2] * isum;
    ov.w = o[4 * q + 3] * isum;
    __builtin_nontemporal_store(ov, o4 + q);
  }
}

// ---------------------------------------------------------------------------
extern "C" void kernel_launch(void* const* d_in, const int* in_sizes, int n_in,
                              void* d_out, int out_size, void* d_ws,
                              size_t ws_size, hipStream_t stream) {
  const float* head_feature = (const float*)d_in[0];
  const float* tail_feature = (const float*)d_in[1];
  const int* edge_index = (const int*)d_in[2];
  const int* tmp_edge = (const int*)d_in[3];
  const float* W = (const float*)d_in[4];
  const float* We = (const float*)d_in[5];
  const float* al = (const float*)d_in[6];
  const float* ar = (const float*)d_in[7];
  const float* ae = (const float*)d_in[8];
  const float* emb = (const float*)d_in[9];
  const float* resW = (const float*)d_in[10];
  const float* resb = (const float*)d_in[11];

  const int C = in_sizes[6];           // 16
  const int IN = in_sizes[4] / C;      // 512
  const int N = in_sizes[0] / IN;      // 100000
  const int E = in_sizes[3];           // 3200000
  const int EF = in_sizes[8];          // 64
  const int NET = in_sizes[9] / EF;    // 8
  const int NB = (N + NPB - 1) / NPB;  // 1563
  (void)C; (void)IN; (void)EF; (void)ws_size; (void)out_size; (void)n_in;

  const int* head = edge_index;
  const int* tail = edge_index + E;

  float* ws = (float*)d_ws;
  float* he = ws;                            // 32 f
  _Float16* Bph = (_Float16*)(he + 32);      // 8192 f16 (16KB)
  _Float16* Bpt = Bph + 8192;                // 8192 f16
  float* wlt = (float*)(Bpt + 8192);         // 512 f
  float* wrt = wlt + 512;                    // 512 f
  float* h_l = wrt + 512;                    // N
  float* h_r = h_l + N;                      // N
  __half* ht = (__half*)(h_r + N);           // 16N halves (32B rows, 3.2MB)
  float* resid = (float*)(ht + (size_t)C_DIM * N);  // 16N f32
  unsigned* rec = (unsigned*)(resid + (size_t)C_DIM * N);  // E u32 (4B rec)
  unsigned* cnt = rec + (size_t)E;           // SCB*CNTW
  unsigned* part = cnt + (size_t)SCB * CNTW;  // NSPL*CNTW
  unsigned* btotal = part + (size_t)NSPL * CNTW;  // NBMAX2
  unsigned* bbase = btotal + NBMAX2;         // NBMAX2+1

  prep_kernel<<<1, 512, 0, stream>>>(W, We, al, ar, ae, emb, resW, he, Bph,
                                     Bpt, wlt, wrt, NET);
  int PB = (N + 63) / 64;
  int chunk = (E + SCB - 1) / SCB;
  projhist_kernel<<<2 * PB + SCB, 256, 0, stream>>>(
      head_feature, tail_feature, Bph, Bpt, wlt, wrt, resid, h_l, ht, h_r, N,
      PB, head, cnt, E, NB, chunk);
  dim3 cg((NB + 255) / 256, NSPL);
  colscanA_kernel<<<cg, 256, 0, stream>>>(cnt, part, NB);
  colscanB_kernel<<<(NB + 255) / 256, 256, 0, stream>>>(part, btotal, NB);
  scan_kernel<<<1, 1024, 0, stream>>>(btotal, bbase, NB);
  scatter_kernel<<<SCB, 512, 0, stream>>>(head, tail, tmp_edge, cnt, part,
                                          bbase, rec, E, NB, chunk);
  agg_kernel<<<NB, 512, 0, stream>>>(rec, bbase, ht, h_l, h_r, he, resid,
                                     resb, (float*)d_out, N, NET);
}

// Round 18
// 201.276 us; speedup vs baseline: 1.3434x; 1.1187x over previous
//
#include <hip/hip_runtime.h>
#include <hip/hip_fp16.h>
#include <math.h>

#define IN_F 512
#define C_DIM 16
#define EF_DIM 64
#define BSHIFT 6     // nodes-per-bucket shift
#define NPB 64       // nodes per bucket; local id fits in 6 bits
#define NBMAX2 2048  // max buckets (N <= 131072: tail fits 17 bits)
#define CNTW 2048    // cnt table row width
#define SCB 512      // scatter/hist partition blocks
#define NSPL 8       // colscan splits (SCB/64)
#define CAP 2560     // per-bucket sorted-record capacity
// record (4B): local(6)[25:20] | type(3)[19:17] | tail(17)[16:0]

typedef float f32x4 __attribute__((ext_vector_type(4)));
typedef _Float16 f16x8 __attribute__((ext_vector_type(8)));

union U2H { unsigned u; __half2 h; };

typedef const unsigned __attribute__((address_space(1)))* gas_u32;
typedef unsigned __attribute__((address_space(3)))* las_u32;

__device__ __forceinline__ void gld16(const float* g, float* l) {
  __builtin_amdgcn_global_load_lds((gas_u32)g, (las_u32)l, 16, 0, 0);
}

// ---------------------------------------------------------------------------
// K0: FUSED prep + hist. Blocks [0,SCB) = per-(block,bucket) histogram
// (scheduled first); block SCB = prep (he[8], wlt/wrt[512], 16KB B tables).
// ---------------------------------------------------------------------------
__global__ __launch_bounds__(512) void prephist_kernel(
    const float* __restrict__ W, const float* __restrict__ We,
    const float* __restrict__ al, const float* __restrict__ ar,
    const float* __restrict__ ae, const float* __restrict__ emb,
    const float* __restrict__ resW, float* __restrict__ he,
    _Float16* __restrict__ Bph, _Float16* __restrict__ Bpt,
    float* __restrict__ wlt, float* __restrict__ wrt, int NET,
    const int* __restrict__ head, unsigned* __restrict__ cnt, int E, int NB,
    int chunk) {
  __shared__ unsigned lcnt[NBMAX2];
  __shared__ float v[EF_DIM];
  int t = threadIdx.x;
  int bid = blockIdx.x;
  if (bid < SCB) {
    // ---- hist role ----
    for (int b = t; b < NB; b += 512) lcnt[b] = 0u;
    __syncthreads();
    int start = bid * chunk;
    int end = min(E, start + chunk);
    for (int i = start + t; i < end; i += 512)
      atomicAdd(
          &lcnt[((unsigned)__builtin_nontemporal_load(head + i)) >> BSHIFT],
          1u);
    __syncthreads();
    unsigned* row = cnt + (size_t)bid * CNTW;
    for (int b = t; b < NB; b += 512) row[b] = lcnt[b];
    return;
  }
  // ---- prep role ----
  float wl = 0.f, wr = 0.f;
#pragma unroll
  for (int c = 0; c < C_DIM; c++) {
    float wv = W[t * C_DIM + c];
    wl += wv * al[c];
    wr += wv * ar[c];
  }
  wlt[t] = wl;
  wrt[t] = wr;
  if (t < EF_DIM) {
    float s = 0.f;
    for (int f = 0; f < EF_DIM; f++) s += We[t * EF_DIM + f] * ae[f];
    v[t] = s;
  }
  __syncthreads();
  if (t < NET) {
    float s = 0.f;
    for (int k = 0; k < EF_DIM; k++) s += emb[t * EF_DIM + k] * v[k];
    he[t] = s;
  }
  for (int i = 0; i < 16; i++) {
    int flat = t + 512 * i;
    int j = flat & 7;
    int l = (flat >> 3) & 63;
    int s = flat >> 9;
    int k = 32 * s + ((l >> 4) << 3) + j;
    int c = l & 15;
    Bph[flat] = (_Float16)resW[k * C_DIM + c];
    Bpt[flat] = (_Float16)W[k * C_DIM + c];
  }
}

// ---------------------------------------------------------------------------
// K1: FUSED scatter + proj. Blocks [0,SCB) = scatter (pure permutation --
// runs FIRST so it overlaps proj instead of trailing it; needs only
// cnt/part/bbase, all computed before this launch). Blocks [SCB, SCB+2PB)
// = proj7 (pinned at the ~3TB/s read-path ceiling; pipes idle -> scatter
// rides free). LDS aliased: proj As[2][4096] (32KB) | scatter 16KB.
// ---------------------------------------------------------------------------
__global__ __launch_bounds__(256) void projscatter_kernel(
    const float* __restrict__ hf, const float* __restrict__ tf,
    const _Float16* __restrict__ Bph, const _Float16* __restrict__ Bpt,
    const float* __restrict__ wlt, const float* __restrict__ wrt,
    float* __restrict__ resid, float* __restrict__ hl,
    __half* __restrict__ ht_, float* __restrict__ hr, int N, int PB,
    const int* __restrict__ head, const int* __restrict__ tail,
    const int* __restrict__ ty, const unsigned* __restrict__ cnt,
    const unsigned* __restrict__ part, const unsigned* __restrict__ bbase,
    unsigned* __restrict__ rec, int E, int NB, int chunk) {
  __shared__ __align__(16) float shmem[8192];  // 32KB
  int t = threadIdx.x;
  int bid = blockIdx.x;
  if (bid < SCB) {
    // ---- scatter role (R15 pure permutation, 256 threads) ----
    unsigned* lbase = (unsigned*)shmem;
    unsigned* lcnt = lbase + NBMAX2;
    const unsigned* row = cnt + (size_t)bid * CNTW;
    const unsigned* prow = part + (size_t)(bid >> 6) * CNTW;
    for (int b = t; b < NB; b += 256) {
      lbase[b] = bbase[b] + prow[b] + row[b];
      lcnt[b] = 0u;
    }
    __syncthreads();
    int start = bid * chunk;
    int end = min(E, start + chunk);
    for (int i = start + t; i < end; i += 256) {
      unsigned h = (unsigned)__builtin_nontemporal_load(head + i);
      unsigned tl = (unsigned)__builtin_nontemporal_load(tail + i);
      unsigned tt = (unsigned)__builtin_nontemporal_load(ty + i);
      unsigned b = h >> BSHIFT;
      unsigned off = atomicAdd(&lcnt[b], 1u);
      rec[lbase[b] + off] = ((h & 63u) << 20) | ((tt & 7u) << 17) | tl;
    }
    return;
  }
  // ---- proj role (proj7, unchanged) ----
  float* As0 = shmem;
  float* As1 = shmem + 4096;
  int w = __builtin_amdgcn_readfirstlane(t >> 6);
  int lane = t & 63;
  int pbid = bid - SCB;
  int by = pbid >= PB ? 1 : 0;
  int r0 = (pbid - by * PB) * 64;
  const float* feat = by ? tf : hf;
  const _Float16* Bp = by ? Bpt : Bph;
  const float* wv = by ? wrt : wlt;
  f32x4 acc0 = {0.f, 0.f, 0.f, 0.f};
  float acc1 = 0.f;
  const float* sg_src[4];
#pragma unroll
  for (int g = 0; g < 4; g++) {
    int u = (w * 4 + g) * 64 + lane;
    int r = u >> 4;
    int c = (u & 15) ^ (r & 7);  // inverse swizzle on global src (rule #21)
    int gr = min(r0 + r, N - 1);
    sg_src[g] = feat + (size_t)gr * IN_F + c * 4;
  }
  int row = w * 16 + (lane & 15);
  int sA[2][2];
#pragma unroll
  for (int s2 = 0; s2 < 2; s2++)
#pragma unroll
    for (int h = 0; h < 2; h++)
      sA[s2][h] = row * 16 + ((s2 * 8 + (lane >> 4) * 2 + h) ^ (row & 7));
  const float* wvp = wv + (lane >> 4) * 8;
#pragma unroll
  for (int g = 0; g < 4; g++) gld16(sg_src[g], As0 + (w * 4 + g) * 256);
  __syncthreads();
#pragma unroll
  for (int kc = 0; kc < 8; kc++) {
    if (kc < 7) {
      float* nb = (kc & 1) ? As0 : As1;
#pragma unroll
      for (int g = 0; g < 4; g++)
        gld16(sg_src[g] + (kc + 1) * 64, nb + (w * 4 + g) * 256);
    }
    const float* ab = (kc & 1) ? As1 : As0;
#pragma unroll
    for (int s2 = 0; s2 < 2; s2++) {
      f32x4 lo = *(const f32x4*)(ab + sA[s2][0] * 4);
      f32x4 hi = *(const f32x4*)(ab + sA[s2][1] * 4);
      f16x8 a = {(_Float16)lo.x, (_Float16)lo.y, (_Float16)lo.z,
                 (_Float16)lo.w, (_Float16)hi.x, (_Float16)hi.y,
                 (_Float16)hi.z, (_Float16)hi.w};
      int s = kc * 2 + s2;
      f16x8 b0 = *(const f16x8*)(Bp + (size_t)(s * 64 + lane) * 8);
      acc0 = __builtin_amdgcn_mfma_f32_16x16x32_f16(a, b0, acc0, 0, 0, 0);
      f32x4 wa = *(const f32x4*)(wvp + kc * 64 + s2 * 32);
      f32x4 wb = *(const f32x4*)(wvp + kc * 64 + s2 * 32 + 4);
      acc1 += lo.x * wa.x + lo.y * wa.y + lo.z * wa.z + lo.w * wa.w +
              hi.x * wb.x + hi.y * wb.y + hi.z * wb.z + hi.w * wb.w;
    }
    __syncthreads();
  }
  acc1 += __shfl_xor(acc1, 16, 64);
  acc1 += __shfl_xor(acc1, 32, 64);
  int col = lane & 15;
  int rb = r0 + w * 16 + (lane >> 4) * 4;
#pragma unroll
  for (int i = 0; i < 4; i++) {
    int r = rb + i;
    if (r < N) {
      if (by == 0)
        resid[(size_t)r * C_DIM + col] = acc0[i];
      else
        ht_[(size_t)r * C_DIM + col] = __float2half(acc0[i]);
    }
  }
  if (lane < 16) {
    int r = r0 + w * 16 + lane;
    if (r < N) {
      if (by == 0)
        hl[r] = acc1;
      else
        hr[r] = acc1;
    }
  }
}

// ---------------------------------------------------------------------------
// K4a: hierarchical column scan, stage A (8 segments of 64 blocks).
// ---------------------------------------------------------------------------
__global__ __launch_bounds__(256) void colscanA_kernel(
    unsigned* __restrict__ cnt, unsigned* __restrict__ part, int NB) {
  int b = blockIdx.x * 256 + threadIdx.x;
  if (b >= NB) return;
  int s = blockIdx.y;
  unsigned running = 0;
#pragma unroll 8
  for (int blk = s * 64; blk < s * 64 + 64; blk++) {
    unsigned v = cnt[(size_t)blk * CNTW + b];
    cnt[(size_t)blk * CNTW + b] = running;
    running += v;
  }
  part[(size_t)s * CNTW + b] = running;
}

// K4b: stage B -- exclusive scan of the 8 segment totals per bucket.
__global__ __launch_bounds__(256) void colscanB_kernel(
    unsigned* __restrict__ part, unsigned* __restrict__ btotal, int NB) {
  int b = blockIdx.x * 256 + threadIdx.x;
  if (b >= NB) return;
  unsigned running = 0;
#pragma unroll
  for (int s = 0; s < NSPL; s++) {
    unsigned v = part[(size_t)s * CNTW + b];
    part[(size_t)s * CNTW + b] = running;
    running += v;
  }
  btotal[b] = running;
}

// ---------------------------------------------------------------------------
// K4c: exclusive scan of bucket totals (<=2048, one block).
// ---------------------------------------------------------------------------
__global__ __launch_bounds__(1024) void scan_kernel(
    const unsigned* __restrict__ btotal, unsigned* __restrict__ base, int NB) {
  __shared__ unsigned ps[1024];
  int t = threadIdx.x;
  unsigned a = (2 * t < NB) ? btotal[2 * t] : 0u;
  unsigned b = (2 * t + 1 < NB) ? btotal[2 * t + 1] : 0u;
  ps[t] = a + b;
  __syncthreads();
  for (int off = 1; off < 1024; off <<= 1) {
    unsigned v = (t >= off) ? ps[t - off] : 0u;
    __syncthreads();
    ps[t] += v;
    __syncthreads();
  }
  unsigned excl = ps[t] - (a + b);
  if (2 * t < NB) base[2 * t] = excl;
  if (2 * t + 1 < NB) base[2 * t + 1] = excl + a;
  if (t == 1023) base[NB] = ps[1023];
}

// ---------------------------------------------------------------------------
// K6: agg v4 (R17 form) -- 512 threads, 8 lanes/node, records in registers,
// logit recomputed here. Zero float atomics; overflow fallback (cold).
// ---------------------------------------------------------------------------
__global__ __launch_bounds__(512) void agg_kernel(
    const unsigned* __restrict__ rec, const unsigned* __restrict__ base,
    const __half* __restrict__ ht, const float* __restrict__ h_l,
    const float* __restrict__ h_r, const float* __restrict__ he_tab,
    const float* __restrict__ resid, const float* __restrict__ resb,
    float* __restrict__ out, int N, int NET) {
  __shared__ unsigned srec[CAP];
  __shared__ unsigned scnt[NPB];
  __shared__ unsigned soff[NPB + 1];
  __shared__ unsigned scur[NPB];
  __shared__ float accf[NPB * 18];
  __shared__ float hl_s[NPB];
  __shared__ float he_s[8];
  int tid = threadIdx.x;
  int b = blockIdx.x;
  int nodebase = b << BSHIFT;
  int s = (int)base[b];
  int e = (int)base[b + 1];
  int cnt_all = e - s;
  int m = min(cnt_all, CAP);
  if (tid < NPB) {
    scnt[tid] = 0u;
    int node = nodebase + tid;
    hl_s[tid] = node < N ? h_l[node] : 0.f;
  }
  if (tid < NET) he_s[tid] = he_tab[tid];
  for (int i = tid; i < NPB * 18; i += 512) accf[i] = 0.f;
  __syncthreads();
  unsigned rv0 = 0, rv1 = 0, rv2 = 0, rv3 = 0, rv4 = 0;
  if (tid < m) rv0 = rec[(size_t)s + tid];
  if (tid + 512 < m) rv1 = rec[(size_t)s + tid + 512];
  if (tid + 1024 < m) rv2 = rec[(size_t)s + tid + 1024];
  if (tid + 1536 < m) rv3 = rec[(size_t)s + tid + 1536];
  if (tid + 2048 < m) rv4 = rec[(size_t)s + tid + 2048];
  if (tid < m) atomicAdd(&scnt[rv0 >> 20], 1u);
  if (tid + 512 < m) atomicAdd(&scnt[rv1 >> 20], 1u);
  if (tid + 1024 < m) atomicAdd(&scnt[rv2 >> 20], 1u);
  if (tid + 1536 < m) atomicAdd(&scnt[rv3 >> 20], 1u);
  if (tid + 2048 < m) atomicAdd(&scnt[rv4 >> 20], 1u);
  __syncthreads();
  if (tid < NPB) {
    unsigned v = scnt[tid];
    unsigned orig = v;
    for (int off = 1; off < NPB; off <<= 1) {
      unsigned u = __shfl_up(v, off, 64);
      if (tid >= off) v += u;
    }
    soff[tid + 1] = v;
    scur[tid] = v - orig;
    if (tid == 0) soff[0] = 0u;
  }
  __syncthreads();
  if (tid < m) srec[atomicAdd(&scur[rv0 >> 20], 1u)] = rv0;
  if (tid + 512 < m) srec[atomicAdd(&scur[rv1 >> 20], 1u)] = rv1;
  if (tid + 1024 < m) srec[atomicAdd(&scur[rv2 >> 20], 1u)] = rv2;
  if (tid + 1536 < m) srec[atomicAdd(&scur[rv3 >> 20], 1u)] = rv3;
  if (tid + 2048 < m) srec[atomicAdd(&scur[rv4 >> 20], 1u)] = rv4;
  for (int i = CAP + tid; i < cnt_all; i += 512) {
    unsigned r = rec[(size_t)(s + i)];
    int local = (int)(r >> 20);
    int typ = (int)((r >> 17) & 7u);
    int tl = (int)(r & 0x1FFFFu);
    float lg = hl_s[local] + h_r[tl] + he_s[typ];
    lg = lg > 0.f ? lg : 0.2f * lg;
    float ex = __expf(lg);
    const uint4* hp = (const uint4*)(ht + (size_t)tl * C_DIM);
    uint4 A = hp[0], B = hp[1];
    float* a = accf + local * 18;
    U2H cv;
    float2 f;
    unsigned wvv[8] = {A.x, A.y, A.z, A.w, B.x, B.y, B.z, B.w};
#pragma unroll
    for (int q = 0; q < 8; q++) {
      cv.u = wvv[q];
      f = __half22float2(cv.h);
      atomicAdd(a + 2 * q, ex * f.x);
      atomicAdd(a + 2 * q + 1, ex * f.y);
    }
    atomicAdd(a + 16, ex);
  }
  __syncthreads();
  int w = tid >> 6;
  int lane = tid & 63;
  int node_l = w * 8 + (lane >> 3);
  int p = lane & 7;
  float a[17];
#pragma unroll
  for (int k = 0; k < 17; k++) a[k] = 0.f;
  int st = (int)soff[node_l];
  int en = (int)soff[node_l + 1];
  float hlv = hl_s[node_l];
  for (int i = st + p; i < en; i += 8) {
    unsigned r = srec[i];
    int typ = (int)((r >> 17) & 7u);
    int tl = (int)(r & 0x1FFFFu);
    float lg = hlv + h_r[tl] + he_s[typ];
    lg = lg > 0.f ? lg : 0.2f * lg;
    float ex = __expf(lg);
    const uint4* hp = (const uint4*)(ht + (size_t)tl * C_DIM);
    uint4 A = hp[0], B = hp[1];
    U2H cv;
    float2 f;
    unsigned wd[8] = {A.x, A.y, A.z, A.w, B.x, B.y, B.z, B.w};
#pragma unroll
    for (int q = 0; q < 8; q++) {
      cv.u = wd[q];
      f = __half22float2(cv.h);
      a[2 * q] += ex * f.x;
      a[2 * q + 1] += ex * f.y;
    }
    a[16] += ex;
  }
#pragma unroll
  for (int k = 0; k < 17; k++) {
    a[k] += __shfl_xor(a[k], 1, 64);
    a[k] += __shfl_xor(a[k], 2, 64);
    a[k] += __shfl_xor(a[k], 4, 64);
  }
  if (p != 0) return;
  int node = nodebase + node_l;
  if (node >= N) return;
  float d = a[16] + accf[node_l * 18 + 16];
  float inv = d > 0.f ? 1.f / d : 0.f;
  const f32x4* r4 = (const f32x4*)(resid + (size_t)node * C_DIM);
  float o[C_DIM];
  float ss = 0.f;
#pragma unroll
  for (int q = 0; q < 4; q++) {
    f32x4 rr = __builtin_nontemporal_load(r4 + q);
    o[4 * q + 0] =
        (a[4 * q + 0] + accf[node_l * 18 + 4 * q + 0]) * inv + rr.x + resb[4 * q + 0];
    o[4 * q + 1] =
        (a[4 * q + 1] + accf[node_l * 18 + 4 * q + 1]) * inv + rr.y + resb[4 * q + 1];
    o[4 * q + 2] =
        (a[4 * q + 2] + accf[node_l * 18 + 4 * q + 2]) * inv + rr.z + resb[4 * q + 2];
    o[4 * q + 3] =
        (a[4 * q + 3] + accf[node_l * 18 + 4 * q + 3]) * inv + rr.w + resb[4 * q + 3];
  }
#pragma unroll
  for (int cc = 0; cc < C_DIM; cc++) ss += o[cc] * o[cc];
  float sc = 1.f / fmaxf(sqrtf(ss), 1e-12f);
  float mx = -1e30f;
#pragma unroll
  for (int cc = 0; cc < C_DIM; cc++) {
    o[cc] *= sc;
    mx = fmaxf(mx, o[cc]);
  }
  float sum = 0.f;
#pragma unroll
  for (int cc = 0; cc < C_DIM; cc++) {
    o[cc] = __expf(o[cc] - mx);
    sum += o[cc];
  }
  float isum = 1.f / sum;
  f32x4* o4 = (f32x4*)(out + (size_t)node * C_DIM);
#pragma unroll
  for (int q = 0; q < 4; q++) {
    f32x4 ov;
    ov.x = o[4 * q] * isum;
    ov.y = o[4 * q + 1] * isum;
    ov.z = o[4 * q + 2] * isum;
    ov.w = o[4 * q + 3] * isum;
    __builtin_nontemporal_store(ov, o4 + q);
  }
}

// ---------------------------------------------------------------------------
extern "C" void kernel_launch(void* const* d_in, const int* in_sizes, int n_in,
                              void* d_out, int out_size, void* d_ws,
                              size_t ws_size, hipStream_t stream) {
  const float* head_feature = (const float*)d_in[0];
  const float* tail_feature = (const float*)d_in[1];
  const int* edge_index = (const int*)d_in[2];
  const int* tmp_edge = (const int*)d_in[3];
  const float* W = (const float*)d_in[4];
  const float* We = (const float*)d_in[5];
  const float* al = (const float*)d_in[6];
  const float* ar = (const float*)d_in[7];
  const float* ae = (const float*)d_in[8];
  const float* emb = (const float*)d_in[9];
  const float* resW = (const float*)d_in[10];
  const float* resb = (const float*)d_in[11];

  const int C = in_sizes[6];           // 16
  const int IN = in_sizes[4] / C;      // 512
  const int N = in_sizes[0] / IN;      // 100000
  const int E = in_sizes[3];           // 3200000
  const int EF = in_sizes[8];          // 64
  const int NET = in_sizes[9] / EF;    // 8
  const int NB = (N + NPB - 1) / NPB;  // 1563
  (void)C; (void)IN; (void)EF; (void)ws_size; (void)out_size; (void)n_in;

  const int* head = edge_index;
  const int* tail = edge_index + E;

  float* ws = (float*)d_ws;
  float* he = ws;                            // 32 f
  _Float16* Bph = (_Float16*)(he + 32);      // 8192 f16 (16KB)
  _Float16* Bpt = Bph + 8192;                // 8192 f16
  float* wlt = (float*)(Bpt + 8192);         // 512 f
  float* wrt = wlt + 512;                    // 512 f
  float* h_l = wrt + 512;                    // N
  float* h_r = h_l + N;                      // N
  __half* ht = (__half*)(h_r + N);           // 16N halves (32B rows, 3.2MB)
  float* resid = (float*)(ht + (size_t)C_DIM * N);  // 16N f32
  unsigned* rec = (unsigned*)(resid + (size_t)C_DIM * N);  // E u32 (4B rec)
  unsigned* cnt = rec + (size_t)E;           // SCB*CNTW
  unsigned* part = cnt + (size_t)SCB * CNTW;  // NSPL*CNTW
  unsigned* btotal = part + (size_t)NSPL * CNTW;  // NBMAX2
  unsigned* bbase = btotal + NBMAX2;         // NBMAX2+1

  int PB = (N + 63) / 64;
  int chunk = (E + SCB - 1) / SCB;
  prephist_kernel<<<SCB + 1, 512, 0, stream>>>(W, We, al, ar, ae, emb, resW,
                                               he, Bph, Bpt, wlt, wrt, NET,
                                               head, cnt, E, NB, chunk);
  dim3 cg((NB + 255) / 256, NSPL);
  colscanA_kernel<<<cg, 256, 0, stream>>>(cnt, part, NB);
  colscanB_kernel<<<(NB + 255) / 256, 256, 0, stream>>>(part, btotal, NB);
  scan_kernel<<<1, 1024, 0, stream>>>(btotal, bbase, NB);
  projscatter_kernel<<<SCB + 2 * PB, 256, 0, stream>>>(
      head_feature, tail_feature, Bph, Bpt, wlt, wrt, resid, h_l, ht, h_r, N,
      PB, head, tail, tmp_edge, cnt, part, bbase, rec, E, NB, chunk);
  agg_kernel<<<NB, 512, 0, stream>>>(rec, bbase, ht, h_l, h_r, he, resid,
                                     resb, (float*)d_out, N, NET);
}